// Round 3
// baseline (1535.459 us; speedup 1.0000x reference)
//
#include <hip/hip_runtime.h>
#include <hip/hip_fp16.h>
#include <cstdint>
#include <cstddef>

// QLinear: per-token int8 quant -> int8 GEMM (MFMA 32x32x32 i8) -> dequant+bias
// R3: R1's 128x128 tile / 6-waves-per-SIMD occupancy (VGPR 84) + R2's XOR bank
// swizzle (16-phase -> 8-phase floor ds_read_b128). R2 post-mortem: 256x128
// tile's 156 VGPRs halved occupancy and regressed 207->268us despite 4x fewer
// conflicts — occupancy dominates at this operating point.

#define MDIM 8192
#define KDIM 4096
#define NDIM 4096

typedef int v4i  __attribute__((ext_vector_type(4)));
typedef int v16i __attribute__((ext_vector_type(16)));

__device__ __forceinline__ void load_lds_16(const void* g, void* l) {
  __builtin_amdgcn_global_load_lds((const __attribute__((address_space(1))) void*)g,
                                   (__attribute__((address_space(3))) void*)l,
                                   16, 0, 0);
}

// ---------------- per-token quantization ----------------
extern "C" __global__ __launch_bounds__(256)
void qlin_quant_x(const float* __restrict__ x, int8_t* __restrict__ xq,
                  float* __restrict__ xs) {
  const int row = blockIdx.x;
  const int t   = threadIdx.x;
  const float4* xr = (const float4*)(x + (size_t)row * KDIM);
  float4 v[4];
  float amax = 0.f;
#pragma unroll
  for (int i = 0; i < 4; ++i) {
    v[i] = xr[t + 256 * i];
    amax = fmaxf(amax, fmaxf(fmaxf(fabsf(v[i].x), fabsf(v[i].y)),
                             fmaxf(fabsf(v[i].z), fabsf(v[i].w))));
  }
#pragma unroll
  for (int off = 32; off > 0; off >>= 1)
    amax = fmaxf(amax, __shfl_xor(amax, off, 64));
  __shared__ float smax[4];
  if ((t & 63) == 0) smax[t >> 6] = amax;
  __syncthreads();
  amax = fmaxf(fmaxf(smax[0], smax[1]), fmaxf(smax[2], smax[3]));
  const float scale = fmaxf(amax, 1e-7f) / 127.0f;  // matches jnp exactly
  if (t == 0) xs[row] = scale;
  int* outp = (int*)(xq + (size_t)row * KDIM);
#pragma unroll
  for (int i = 0; i < 4; ++i) {
    // rintf = round-half-even = jnp.round; exact division matches x / x_scale
    int q0 = (int)rintf(v[i].x / scale);
    int q1 = (int)rintf(v[i].y / scale);
    int q2 = (int)rintf(v[i].z / scale);
    int q3 = (int)rintf(v[i].w / scale);
    q0 = min(127, max(-128, q0));
    q1 = min(127, max(-128, q1));
    q2 = min(127, max(-128, q2));
    q3 = min(127, max(-128, q3));
    outp[t + 256 * i] = (q0 & 0xff) | ((q1 & 0xff) << 8) |
                        ((q2 & 0xff) << 16) | ((q3 & 0xff) << 24);
  }
}

// ---------------- weight int32 -> int8 repack ----------------
extern "C" __global__ __launch_bounds__(256)
void qlin_pack_w(const int* __restrict__ w32, int8_t* __restrict__ w8) {
  const int idx = blockIdx.x * 256 + threadIdx.x;
  const int4 w = ((const int4*)w32)[idx];
  ((int*)w8)[idx] = (w.x & 0xff) | ((w.y & 0xff) << 8) |
                    ((w.z & 0xff) << 16) | ((w.w & 0xff) << 24);
}

// ---------------- int8 GEMM, 128x128 tile, BK=64, mfma_i32_32x32x32_i8 ----
// 4 waves in 2x2; wave quadrant 64x64 = 2x2 MFMA tiles.
// LDS XOR swizzle: LDS[row][slot] holds global 16B chunk slot^((row>>1)&3)
// (staging permutes the GLOBAL source chunk since global_load_lds forces
// dest = base + tid*16). Reads XOR their byte offset with ((r>>1)&3)<<4,
// spreading the 8 lanes-per-bank-quad evenly -> 8-phase (floor) b128 reads.
extern "C" __global__ __launch_bounds__(256, 6)
void qlin_gemm(const int8_t* __restrict__ Aq, const int8_t* __restrict__ Bq,
               const float* __restrict__ xs, const float* __restrict__ ws,
               const float* __restrict__ bias, float* __restrict__ out) {
  __shared__ int8_t As[128 * 64];
  __shared__ int8_t Bs[128 * 64];
  const int tid  = threadIdx.x;
  const int lane = tid & 63;
  const int wave = tid >> 6;
  const int wr   = wave >> 1;
  const int wc   = wave & 1;
  const int m0   = blockIdx.y * 128;
  const int n0   = blockIdx.x * 128;

  // staging: thread tid covers rows srow / srow+64; LDS slot tid&3; global
  // chunk permuted: (tid&3) ^ ((row>>1)&3) == (tid&3) ^ ((tid>>3)&3).
  const int srow   = tid >> 2;
  const int gchunk = ((tid & 3) ^ ((tid >> 3) & 3)) * 16;

  const int8_t* Ab = Aq + (size_t)m0 * KDIM;
  const int8_t* Bb = Bq + (size_t)n0 * KDIM;

  v16i acc[2][2];
#pragma unroll
  for (int i = 0; i < 2; ++i)
#pragma unroll
    for (int j = 0; j < 2; ++j)
#pragma unroll
      for (int r = 0; r < 16; ++r) acc[i][j][r] = 0;

  const int r    = lane & 31;
  const int g    = (lane >> 5) * 16;       // k-half across lane>>5
  const int rswz = ((r >> 1) & 3) << 4;    // read-side XOR swizzle
  const int off0 = g ^ rswz;               // ks=0 byte offset (precomputed)
  const int off1 = (32 + g) ^ rswz;        // ks=1
  const int aRow = (wr * 64 + r) * 64;     // + i*2048 folds into imm offset
  const int bRow = (wc * 64 + r) * 64;

  for (int k0 = 0; k0 < KDIM; k0 += 64) {
    load_lds_16(Ab + (size_t)srow * KDIM + (k0 + gchunk), As + tid * 16);
    load_lds_16(Ab + (size_t)(srow + 64) * KDIM + (k0 + gchunk), As + 4096 + tid * 16);
    load_lds_16(Bb + (size_t)srow * KDIM + (k0 + gchunk), Bs + tid * 16);
    load_lds_16(Bb + (size_t)(srow + 64) * KDIM + (k0 + gchunk), Bs + 4096 + tid * 16);
    __builtin_amdgcn_s_waitcnt(0);
    __syncthreads();

    {
      v4i a[2], b[2];
#pragma unroll
      for (int i = 0; i < 2; ++i)
        a[i] = *(const v4i*)(As + aRow + i * 2048 + off0);
#pragma unroll
      for (int j = 0; j < 2; ++j)
        b[j] = *(const v4i*)(Bs + bRow + j * 2048 + off0);
#pragma unroll
      for (int i = 0; i < 2; ++i)
#pragma unroll
        for (int j = 0; j < 2; ++j)
          acc[i][j] = __builtin_amdgcn_mfma_i32_32x32x32_i8(a[i], b[j], acc[i][j], 0, 0, 0);
#pragma unroll
      for (int i = 0; i < 2; ++i)
        a[i] = *(const v4i*)(As + aRow + i * 2048 + off1);
#pragma unroll
      for (int j = 0; j < 2; ++j)
        b[j] = *(const v4i*)(Bs + bRow + j * 2048 + off1);
#pragma unroll
      for (int i = 0; i < 2; ++i)
#pragma unroll
        for (int j = 0; j < 2; ++j)
          acc[i][j] = __builtin_amdgcn_mfma_i32_32x32x32_i8(a[i], b[j], acc[i][j], 0, 0, 0);
    }
    __syncthreads();
  }

  // epilogue: C/D layout col=lane&31, row=(reg&3)+8*(reg>>2)+4*(lane>>5)
  const int col = lane & 31;
  const int rb  = (lane >> 5) * 4;
#pragma unroll
  for (int j = 0; j < 2; ++j) {
    const int gc = n0 + wc * 64 + j * 32 + col;
    const float wsv = ws[gc];
    const float bv  = bias[gc];
#pragma unroll
    for (int i = 0; i < 2; ++i) {
      const int grb = m0 + wr * 64 + i * 32 + rb;
#pragma unroll
      for (int reg = 0; reg < 16; ++reg) {
        const int gr = grb + (reg & 3) + 8 * (reg >> 2);
        float t = (float)acc[i][j][reg] * xs[gr];
        t = t * wsv + bv;
        out[(size_t)gr * NDIM + gc] = __half2float(__float2half(t));
      }
    }
  }
}

extern "C" void kernel_launch(void* const* d_in, const int* in_sizes, int n_in,
                              void* d_out, int out_size, void* d_ws, size_t ws_size,
                              hipStream_t stream) {
  const float* x      = (const float*)d_in[0];
  const int*   wq32   = (const int*)d_in[1];    // int8 promoted to int32
  const float* wscale = (const float*)d_in[2];
  const float* bias   = (const float*)d_in[3];  // fp16 promoted to fp32
  float*       out    = (float*)d_out;

  int8_t* xq = (int8_t*)d_ws;                                    // 32 MiB
  int8_t* w8 = (int8_t*)d_ws + (size_t)MDIM * KDIM;              // 16 MiB
  float*  xs = (float*)((int8_t*)d_ws + (size_t)MDIM * KDIM + (size_t)NDIM * KDIM);

  qlin_quant_x<<<MDIM, 256, 0, stream>>>(x, xq, xs);
  qlin_pack_w<<<(NDIM * KDIM / 4) / 256, 256, 0, stream>>>(wq32, w8);
  qlin_gemm<<<dim3(NDIM / 128, MDIM / 128), 256, 0, stream>>>(xq, w8, xs, wscale, bias, out);
}

// Round 4
// 442.733 us; speedup vs baseline: 3.4681x; 3.4681x over previous
//
#include <hip/hip_runtime.h>
#include <hip/hip_fp16.h>
#include <cstdint>
#include <cstddef>

// QLinear: per-token int8 quant -> int8 GEMM (MFMA 32x32x32 i8) -> dequant+bias
// R4 = R1 (128x128 tile, 84 VGPR, 207us) + R2's XOR bank swizzle ONLY.
// R3 post-mortem: __launch_bounds__(256,6) forced VGPR=40 -> accumulator
// spilled to scratch inside K-loop (FETCH 2.4GB / WRITE 3.6GB of spill
// traffic, 1306us). NEVER pass a min-waves bound tighter than the acc
// working set. R3 did confirm swizzle hits 1.68e7 conflicts (vs 5.03e7).

#define MDIM 8192
#define KDIM 4096
#define NDIM 4096

typedef int v4i  __attribute__((ext_vector_type(4)));
typedef int v16i __attribute__((ext_vector_type(16)));

__device__ __forceinline__ void load_lds_16(const void* g, void* l) {
  __builtin_amdgcn_global_load_lds((const __attribute__((address_space(1))) void*)g,
                                   (__attribute__((address_space(3))) void*)l,
                                   16, 0, 0);
}

// ---------------- per-token quantization ----------------
extern "C" __global__ __launch_bounds__(256)
void qlin_quant_x(const float* __restrict__ x, int8_t* __restrict__ xq,
                  float* __restrict__ xs) {
  const int row = blockIdx.x;
  const int t   = threadIdx.x;
  const float4* xr = (const float4*)(x + (size_t)row * KDIM);
  float4 v[4];
  float amax = 0.f;
#pragma unroll
  for (int i = 0; i < 4; ++i) {
    v[i] = xr[t + 256 * i];
    amax = fmaxf(amax, fmaxf(fmaxf(fabsf(v[i].x), fabsf(v[i].y)),
                             fmaxf(fabsf(v[i].z), fabsf(v[i].w))));
  }
#pragma unroll
  for (int off = 32; off > 0; off >>= 1)
    amax = fmaxf(amax, __shfl_xor(amax, off, 64));
  __shared__ float smax[4];
  if ((t & 63) == 0) smax[t >> 6] = amax;
  __syncthreads();
  amax = fmaxf(fmaxf(smax[0], smax[1]), fmaxf(smax[2], smax[3]));
  const float scale = fmaxf(amax, 1e-7f) / 127.0f;  // matches jnp exactly
  if (t == 0) xs[row] = scale;
  int* outp = (int*)(xq + (size_t)row * KDIM);
#pragma unroll
  for (int i = 0; i < 4; ++i) {
    // rintf = round-half-even = jnp.round; exact division matches x / x_scale
    int q0 = (int)rintf(v[i].x / scale);
    int q1 = (int)rintf(v[i].y / scale);
    int q2 = (int)rintf(v[i].z / scale);
    int q3 = (int)rintf(v[i].w / scale);
    q0 = min(127, max(-128, q0));
    q1 = min(127, max(-128, q1));
    q2 = min(127, max(-128, q2));
    q3 = min(127, max(-128, q3));
    outp[t + 256 * i] = (q0 & 0xff) | ((q1 & 0xff) << 8) |
                        ((q2 & 0xff) << 16) | ((q3 & 0xff) << 24);
  }
}

// ---------------- weight int32 -> int8 repack ----------------
extern "C" __global__ __launch_bounds__(256)
void qlin_pack_w(const int* __restrict__ w32, int8_t* __restrict__ w8) {
  const int idx = blockIdx.x * 256 + threadIdx.x;
  const int4 w = ((const int4*)w32)[idx];
  ((int*)w8)[idx] = (w.x & 0xff) | ((w.y & 0xff) << 8) |
                    ((w.z & 0xff) << 16) | ((w.w & 0xff) << 24);
}

// ---------------- int8 GEMM, 128x128 tile, BK=64, mfma_i32_32x32x32_i8 ----
// 4 waves; wave (wr,wc) owns a 64x64 quadrant as 2x2 tiles of 32x32.
// LDS XOR swizzle: LDS[row][slot] holds global 16B chunk slot^((row>>1)&3)
// (staging permutes the GLOBAL source chunk since global_load_lds forces
// dest = base + tid*16). Reads XOR their byte offset with ((r>>1)&3)<<4.
extern "C" __global__ __launch_bounds__(256)
void qlin_gemm(const int8_t* __restrict__ Aq, const int8_t* __restrict__ Bq,
               const float* __restrict__ xs, const float* __restrict__ ws,
               const float* __restrict__ bias, float* __restrict__ out) {
  __shared__ int8_t As[128 * 64];
  __shared__ int8_t Bs[128 * 64];
  const int tid  = threadIdx.x;
  const int lane = tid & 63;
  const int wave = tid >> 6;
  const int wr   = wave >> 1;
  const int wc   = wave & 1;
  const int m0   = blockIdx.y * 128;
  const int n0   = blockIdx.x * 128;

  const int srow   = tid >> 2;
  const int gchunk = ((tid & 3) ^ ((tid >> 3) & 3)) * 16;

  const int8_t* Ab = Aq + (size_t)m0 * KDIM;
  const int8_t* Bb = Bq + (size_t)n0 * KDIM;

  v16i acc[2][2];
#pragma unroll
  for (int i = 0; i < 2; ++i)
#pragma unroll
    for (int j = 0; j < 2; ++j)
#pragma unroll
      for (int r = 0; r < 16; ++r) acc[i][j][r] = 0;

  const int r    = lane & 31;
  const int g    = (lane >> 5) * 16;       // k-half across lane>>5
  const int rswz = ((r >> 1) & 3) << 4;    // read-side XOR swizzle

  for (int k0 = 0; k0 < KDIM; k0 += 64) {
    load_lds_16(Ab + (size_t)srow * KDIM + (k0 + gchunk), As + tid * 16);
    load_lds_16(Ab + (size_t)(srow + 64) * KDIM + (k0 + gchunk), As + 4096 + tid * 16);
    load_lds_16(Bb + (size_t)srow * KDIM + (k0 + gchunk), Bs + tid * 16);
    load_lds_16(Bb + (size_t)(srow + 64) * KDIM + (k0 + gchunk), Bs + 4096 + tid * 16);
    __builtin_amdgcn_s_waitcnt(0);
    __syncthreads();

#pragma unroll
    for (int ks = 0; ks < 2; ++ks) {
      const int koff = (ks * 32 + g) ^ rswz;
      v4i a[2], b[2];
#pragma unroll
      for (int i = 0; i < 2; ++i)
        a[i] = *(const v4i*)(As + (wr * 64 + i * 32 + r) * 64 + koff);
#pragma unroll
      for (int j = 0; j < 2; ++j)
        b[j] = *(const v4i*)(Bs + (wc * 64 + j * 32 + r) * 64 + koff);
#pragma unroll
      for (int i = 0; i < 2; ++i)
#pragma unroll
        for (int j = 0; j < 2; ++j)
          acc[i][j] = __builtin_amdgcn_mfma_i32_32x32x32_i8(a[i], b[j], acc[i][j], 0, 0, 0);
    }
    __syncthreads();
  }

  // epilogue: C/D layout col=lane&31, row=(reg&3)+8*(reg>>2)+4*(lane>>5)
  const int col = lane & 31;
  const int rb  = (lane >> 5) * 4;
#pragma unroll
  for (int j = 0; j < 2; ++j) {
    const int gc = n0 + wc * 64 + j * 32 + col;
    const float wsv = ws[gc];
    const float bv  = bias[gc];
#pragma unroll
    for (int i = 0; i < 2; ++i) {
      const int grb = m0 + wr * 64 + i * 32 + rb;
#pragma unroll
      for (int reg = 0; reg < 16; ++reg) {
        const int gr = grb + (reg & 3) + 8 * (reg >> 2);
        float t = (float)acc[i][j][reg] * xs[gr];
        t = t * wsv + bv;
        out[(size_t)gr * NDIM + gc] = __half2float(__float2half(t));
      }
    }
  }
}

extern "C" void kernel_launch(void* const* d_in, const int* in_sizes, int n_in,
                              void* d_out, int out_size, void* d_ws, size_t ws_size,
                              hipStream_t stream) {
  const float* x      = (const float*)d_in[0];
  const int*   wq32   = (const int*)d_in[1];    // int8 promoted to int32
  const float* wscale = (const float*)d_in[2];
  const float* bias   = (const float*)d_in[3];  // fp16 promoted to fp32
  float*       out    = (float*)d_out;

  int8_t* xq = (int8_t*)d_ws;                                    // 32 MiB
  int8_t* w8 = (int8_t*)d_ws + (size_t)MDIM * KDIM;              // 16 MiB
  float*  xs = (float*)((int8_t*)d_ws + (size_t)MDIM * KDIM + (size_t)NDIM * KDIM);

  qlin_quant_x<<<MDIM, 256, 0, stream>>>(x, xq, xs);
  qlin_pack_w<<<(NDIM * KDIM / 4) / 256, 256, 0, stream>>>(wq32, w8);
  qlin_gemm<<<dim3(NDIM / 128, MDIM / 128), 256, 0, stream>>>(xq, w8, xs, wscale, bias, out);
}